// Round 4
// baseline (325.251 us; speedup 1.0000x reference)
//
#include <hip/hip_runtime.h>
#include <math.h>

#define N_NODES 100000
#define N_EDGES 1600000
#define F_IN    16
#define H_DIM   32
#define B_GRAPHS 256

#define BSHIFT  7
#define BSIZE   128                                   // nodes per bucket
#define NBUCKET ((N_NODES + BSIZE - 1) / BSIZE)       // 782
#define EPB     8192                                  // edges per chunk block
#define NCHUNK  ((N_EDGES + EPB - 1) / EPB)           // 196
#define CAPB    2560                                  // fixed bucket stride (mean 2048, +11 sigma)
#define CSTRIDE 2944                                  // csr entries reserved per bucket (2560+384)
#define TPAD    (NBUCKET * CSTRIDE)
#define CURSTR  16                                    // bucket_cur stride: 1 counter / 64B line
#define NPB     32                                    // nodes per layer block (8 lanes/node)
#define LAYER_BLOCKS (N_NODES / NPB)                  // 3125

// ---------------------------------------------------------------------------
__device__ inline float bf_lo(unsigned u) { return __uint_as_float(u << 16); }
__device__ inline float bf_hi(unsigned u) { return __uint_as_float(u & 0xffff0000u); }
__device__ inline unsigned pack_bf16x2(float a, float b) {
    unsigned ua = __float_as_uint(a), ub = __float_as_uint(b);
    ua += 0x7fffu + ((ua >> 16) & 1u);    // RNE
    ub += 0x7fffu + ((ub >> 16) & 1u);
    return (ua >> 16) | (ub & 0xffff0000u);
}
// monotone float<->uint for atomicMax on floats (no NaN inputs: tanh outputs)
__device__ inline unsigned fenc(float f) {
    unsigned u = __float_as_uint(f);
    return (u & 0x80000000u) ? ~u : (u | 0x80000000u);
}
__device__ inline float fdec(unsigned k) {
    if (k == 0u) return -INFINITY;        // empty segment sentinel
    return __uint_as_float((k & 0x80000000u) ? (k ^ 0x80000000u) : ~k);
}
// nontemporal int4 load (csr is streamed once per layer -> keep L2 for h)
typedef int v4i __attribute__((ext_vector_type(4)));
__device__ inline int4 ntload4(const int4* p) {
    v4i r = __builtin_nontemporal_load((const v4i*)p);
    int4 o; o.x = r.x; o.y = r.y; o.z = r.z; o.w = r.w; return o;
}

// ---------------------------------------------------------------------------
// Init: bucket claim counters + pooling accumulators.
__global__ __launch_bounds__(256) void init_kernel(int* __restrict__ bucket_cur,
                                                   unsigned* __restrict__ gmaxk,
                                                   float* __restrict__ gsum,
                                                   int* __restrict__ gcnt) {
    int t = blockIdx.x * 256 + threadIdx.x;
    if (t < NBUCKET) bucket_cur[t * CURSTR] = t * CAPB;
    if (t < B_GRAPHS * H_DIM) { gmaxk[t] = 0u; gsum[t] = 0.f; }
    if (t < B_GRAPHS) gcnt[t] = 0;
}

// Pass B: per-block histogram -> claim per-bucket runs -> direct scattered
// writes. Record = src | dst_local<<20.
__global__ __launch_bounds__(1024) void passB_kernel(const int* __restrict__ ei,
                                                     int* __restrict__ bucket_cur,
                                                     unsigned* __restrict__ rec_out) {
    __shared__ int hist[NBUCKET];
    __shared__ int gcur[NBUCKET];
    int t = threadIdx.x;
    for (int k = t; k < NBUCKET; k += 1024) hist[k] = 0;
    __syncthreads();

    const int* dst = ei + N_EDGES;
    int base = blockIdx.x * EPB;
    int end  = base + EPB; if (end > N_EDGES) end = N_EDGES;

    for (int e = base + t; e < end; e += 1024) atomicAdd(&hist[dst[e] >> BSHIFT], 1);
    __syncthreads();

    for (int k = t; k < NBUCKET; k += 1024) {
        int h = hist[k];
        gcur[k] = h ? atomicAdd(&bucket_cur[k * CURSTR], h) : 0;
    }
    __syncthreads();

    for (int e = base + t; e < end; e += 1024) {
        int d = dst[e], s = ei[e];
        int bk = d >> BSHIFT;
        int pos = atomicAdd(&gcur[bk], 1);
        rec_out[pos] = (unsigned)s | ((unsigned)(d & (BSIZE - 1)) << 20);
    }
}

// Per-bucket in-degree -> dinv (LDS atomics over the bucket's rec run).
__global__ __launch_bounds__(256) void dinv_kernel(const unsigned* __restrict__ rec,
                                                   const int* __restrict__ bucket_cur,
                                                   float* __restrict__ dinv) {
    __shared__ int cnt[BSIZE];
    int t = threadIdx.x, b = blockIdx.x;
    if (t < BSIZE) cnt[t] = 0;
    __syncthreads();
    int e1 = bucket_cur[b * CURSTR];
    for (int e = b * CAPB + t; e < e1; e += 256) atomicAdd(&cnt[rec[e] >> 20], 1);
    __syncthreads();
    int nd = (b << BSHIFT) + t;
    if (t < BSIZE && nd < N_NODES) dinv[nd] = rsqrtf((float)cnt[t] + 1.0f);
}

// Pass C: per-bucket node sort into padded interleaved CSR: entry=(src,coef).
// Rows padded to multiples of 4; dummy entries use the row's OWN node as src
// (coef=0). row_meta=(start,padded_len).
__global__ __launch_bounds__(256) void passC_kernel(const unsigned* __restrict__ rec,
                                                    const int* __restrict__ bucket_cur,
                                                    const float* __restrict__ dinv,
                                                    int2* __restrict__ row_meta,
                                                    int2* __restrict__ csr) {
    __shared__ unsigned stage[CAPB];
    __shared__ int cnt[BSIZE];
    __shared__ int pds[BSIZE];
    __shared__ int cur[BSIZE];
    __shared__ float sdv[BSIZE];
    int t = threadIdx.x, b = blockIdx.x;
    int node0 = b << BSHIFT;
    int e0 = b * CAPB;
    int n = bucket_cur[b * CURSTR] - e0;
    int pbase = b * CSTRIDE;              // 8-aligned (CSTRIDE % 8 == 0)
    if (t < BSIZE) {
        cnt[t] = 0;
        int nd = node0 + t;
        sdv[t] = (nd < N_NODES) ? dinv[nd] : 0.f;
    }
    __syncthreads();
    for (int k = t; k < n; k += 256) {
        unsigned r = rec[e0 + k];
        stage[k] = r;
        atomicAdd(&cnt[r >> 20], 1);
    }
    __syncthreads();
    // inclusive scan of pad-4 counts
    int pd = 0;
    if (t < BSIZE) { pd = (cnt[t] + 3) & ~3; pds[t] = pd; }
    __syncthreads();
    for (int off = 1; off < BSIZE; off <<= 1) {
        int v = (t < BSIZE && t >= off) ? pds[t - off] : 0;
        __syncthreads();
        if (t < BSIZE) pds[t] += v;
        __syncthreads();
    }
    if (t < BSIZE) {
        int startp = pbase + pds[t] - pd;
        cur[t] = startp;
        int nd = node0 + t;
        if (nd < N_NODES) {
            row_meta[nd] = make_int2(startp, pd);
            for (int k = startp + cnt[t]; k < startp + pd; ++k)
                csr[k] = make_int2(nd, 0);   // dummy: own node, coef 0
        }
    }
    __syncthreads();
    for (int k = t; k < n; k += 256) {
        unsigned r = stage[k];
        int dl = r >> 20;
        int s  = r & 0xFFFFF;
        int pos = atomicAdd(&cur[dl], 1);
        csr[pos] = make_int2(s, __float_as_int(dinv[s] * sdv[dl]));
    }
}

// ---------------------------------------------------------------------------
// GCN layer, 8 lanes/node: each lane loads 2 consecutive dwords (8B) of the
// gathered row -> a wave covers 8 nodes, halving VMEM instruction count and
// doubling per-thread bytes in flight vs the 16-lane layout. csr loads are
// nontemporal (streamed once -> don't evict h from L2). Fused W+bias+tanh;
// POOL variant merges per-graph max/sum/count via global atomics.
template <int FIN, bool PACKED, bool POOL>
__global__ __launch_bounds__(256) void layer_kernel(
        const void* __restrict__ h_in_v,
        const int2* __restrict__ row_meta,
        const int4* __restrict__ csr4,     // 2 edges per int4
        const float* __restrict__ dinv,
        const float* __restrict__ W,       // [FIN][32]
        const float* __restrict__ bias,    // [32]
        unsigned* __restrict__ h_out,
        const int* __restrict__ batch,
        unsigned* __restrict__ gmaxk,
        float* __restrict__ gsum,
        int* __restrict__ gcnt) {
    constexpr int STR = FIN + 1;
    __shared__ float sW[FIN * H_DIM];
    __shared__ float sb[H_DIM];
    __shared__ float agg[NPB][STR];
    __shared__ int sg[NPB];
    int t = threadIdx.x;
    for (int k = t; k < FIN * H_DIM; k += 256) sW[k] = W[k];
    if (t < H_DIM) sb[t] = bias[t];

    int nl = t >> 3, ln = t & 7;          // 32 nodes/block, 8 lanes/node
    int d0 = 2 * ln;                      // lane's dword pair within a row
    int i = blockIdx.x * NPB + nl;
    int2 m = row_meta[i];
    float di = dinv[i], di2 = di * di;
    int q    = m.x >> 1;                  // int4 index of row start
    int qend = (m.x + m.y) >> 1;

    if (PACKED) {
        const unsigned* hp = (const unsigned*)h_in_v;
        uint2 su = *(const uint2*)(hp + i * 16 + d0);
        float a0 = bf_lo(su.x) * di2, a1 = bf_hi(su.x) * di2;
        float a2 = bf_lo(su.y) * di2, a3 = bf_hi(su.y) * di2;
        for (; q + 8 <= qend; q += 8) {     // 16 edges in flight
            int4 ca[8];
#pragma unroll
            for (int k = 0; k < 8; ++k) ca[k] = ntload4(csr4 + q + k);
            uint2 v[16];
#pragma unroll
            for (int k = 0; k < 8; ++k) {
                v[2 * k]     = *(const uint2*)(hp + ca[k].x * 16 + d0);
                v[2 * k + 1] = *(const uint2*)(hp + ca[k].z * 16 + d0);
            }
#pragma unroll
            for (int k = 0; k < 8; ++k) {
                float c0 = __int_as_float(ca[k].y), c1 = __int_as_float(ca[k].w);
                a0 += bf_lo(v[2 * k].x) * c0 + bf_lo(v[2 * k + 1].x) * c1;
                a1 += bf_hi(v[2 * k].x) * c0 + bf_hi(v[2 * k + 1].x) * c1;
                a2 += bf_lo(v[2 * k].y) * c0 + bf_lo(v[2 * k + 1].y) * c1;
                a3 += bf_hi(v[2 * k].y) * c0 + bf_hi(v[2 * k + 1].y) * c1;
            }
        }
        if (q + 4 <= qend) {                // 8-edge tail
            int4 ca[4];
#pragma unroll
            for (int k = 0; k < 4; ++k) ca[k] = ntload4(csr4 + q + k);
#pragma unroll
            for (int k = 0; k < 4; ++k) {
                uint2 v0 = *(const uint2*)(hp + ca[k].x * 16 + d0);
                uint2 v1 = *(const uint2*)(hp + ca[k].z * 16 + d0);
                float c0 = __int_as_float(ca[k].y), c1 = __int_as_float(ca[k].w);
                a0 += bf_lo(v0.x) * c0 + bf_lo(v1.x) * c1;
                a1 += bf_hi(v0.x) * c0 + bf_hi(v1.x) * c1;
                a2 += bf_lo(v0.y) * c0 + bf_lo(v1.y) * c1;
                a3 += bf_hi(v0.y) * c0 + bf_hi(v1.y) * c1;
            }
            q += 4;
        }
        if (q < qend) {                     // 4-edge tail (2 int4s)
            int4 a = ntload4(csr4 + q), b = ntload4(csr4 + q + 1);
            uint2 v0 = *(const uint2*)(hp + a.x * 16 + d0);
            uint2 v1 = *(const uint2*)(hp + a.z * 16 + d0);
            uint2 v2 = *(const uint2*)(hp + b.x * 16 + d0);
            uint2 v3 = *(const uint2*)(hp + b.z * 16 + d0);
            float c0 = __int_as_float(a.y), c1 = __int_as_float(a.w);
            float c2 = __int_as_float(b.y), c3 = __int_as_float(b.w);
            a0 += bf_lo(v0.x) * c0 + bf_lo(v1.x) * c1 + bf_lo(v2.x) * c2 + bf_lo(v3.x) * c3;
            a1 += bf_hi(v0.x) * c0 + bf_hi(v1.x) * c1 + bf_hi(v2.x) * c2 + bf_hi(v3.x) * c3;
            a2 += bf_lo(v0.y) * c0 + bf_lo(v1.y) * c1 + bf_lo(v2.y) * c2 + bf_lo(v3.y) * c3;
            a3 += bf_hi(v0.y) * c0 + bf_hi(v1.y) * c1 + bf_hi(v2.y) * c2 + bf_hi(v3.y) * c3;
        }
        agg[nl][4 * ln]     = a0;          // features 4*ln .. 4*ln+3
        agg[nl][4 * ln + 1] = a1;
        agg[nl][4 * ln + 2] = a2;
        agg[nl][4 * ln + 3] = a3;
    } else {
        const float* xf = (const float*)h_in_v;
        float2 sx = *(const float2*)(xf + i * F_IN + d0);
        float a0 = sx.x * di2, a1 = sx.y * di2;
        for (; q + 8 <= qend; q += 8) {
            int4 ca[8];
#pragma unroll
            for (int k = 0; k < 8; ++k) ca[k] = ntload4(csr4 + q + k);
            float2 v[16];
#pragma unroll
            for (int k = 0; k < 8; ++k) {
                v[2 * k]     = *(const float2*)(xf + ca[k].x * F_IN + d0);
                v[2 * k + 1] = *(const float2*)(xf + ca[k].z * F_IN + d0);
            }
#pragma unroll
            for (int k = 0; k < 8; ++k) {
                float c0 = __int_as_float(ca[k].y), c1 = __int_as_float(ca[k].w);
                a0 += v[2 * k].x * c0 + v[2 * k + 1].x * c1;
                a1 += v[2 * k].y * c0 + v[2 * k + 1].y * c1;
            }
        }
        if (q + 4 <= qend) {
            int4 ca[4];
#pragma unroll
            for (int k = 0; k < 4; ++k) ca[k] = ntload4(csr4 + q + k);
#pragma unroll
            for (int k = 0; k < 4; ++k) {
                float2 v0 = *(const float2*)(xf + ca[k].x * F_IN + d0);
                float2 v1 = *(const float2*)(xf + ca[k].z * F_IN + d0);
                float c0 = __int_as_float(ca[k].y), c1 = __int_as_float(ca[k].w);
                a0 += v0.x * c0 + v1.x * c1;
                a1 += v0.y * c0 + v1.y * c1;
            }
            q += 4;
        }
        if (q < qend) {
            int4 a = ntload4(csr4 + q), b = ntload4(csr4 + q + 1);
            float2 v0 = *(const float2*)(xf + a.x * F_IN + d0);
            float2 v1 = *(const float2*)(xf + a.z * F_IN + d0);
            float2 v2 = *(const float2*)(xf + b.x * F_IN + d0);
            float2 v3 = *(const float2*)(xf + b.z * F_IN + d0);
            a0 += v0.x * __int_as_float(a.y) + v1.x * __int_as_float(a.w)
                + v2.x * __int_as_float(b.y) + v3.x * __int_as_float(b.w);
            a1 += v0.y * __int_as_float(a.y) + v1.y * __int_as_float(a.w)
                + v2.y * __int_as_float(b.y) + v3.y * __int_as_float(b.w);
        }
        agg[nl][d0]     = a0;              // features 2*ln, 2*ln+1
        agg[nl][d0 + 1] = a1;
    }
    __syncthreads();

    // transform + bias + tanh  (32 nodes x 8 lanes x 4 outputs)
    int j0 = 4 * ln;
    float o0 = sb[j0], o1 = sb[j0 + 1], o2 = sb[j0 + 2], o3 = sb[j0 + 3];
    const float* arow = &agg[nl][0];
#pragma unroll
    for (int k = 0; k < FIN; ++k) {
        float a = arow[k];
        o0 += a * sW[k * H_DIM + j0];
        o1 += a * sW[k * H_DIM + j0 + 1];
        o2 += a * sW[k * H_DIM + j0 + 2];
        o3 += a * sW[k * H_DIM + j0 + 3];
    }
    float t0 = tanhf(o0), t1 = tanhf(o1), t2 = tanhf(o2), t3 = tanhf(o3);

    if (!POOL) {
        uint2 pk;
        pk.x = pack_bf16x2(t0, t1);
        pk.y = pack_bf16x2(t2, t3);
        *(uint2*)(h_out + i * 16 + d0) = pk;
    } else {
        __syncthreads();                   // all agg reads done before reuse
        agg[nl][j0]     = t0;              // stage h values [node][feat]
        agg[nl][j0 + 1] = t1;
        agg[nl][j0 + 2] = t2;
        agg[nl][j0 + 3] = t3;
        if (t < NPB) sg[t] = batch[blockIdx.x * NPB + t];
        __syncthreads();
        if (t < H_DIM) {                   // segmented reduce over 32 sorted nodes
            int j = t;
            int g = sg[0];
            float mx = agg[0][j], sm = mx;
            int run = 1;
            for (int nn = 1; nn < NPB; ++nn) {
                float v = agg[nn][j];
                if (sg[nn] != g) {
                    atomicMax(&gmaxk[g * H_DIM + j], fenc(mx));
                    atomicAdd(&gsum[g * H_DIM + j], sm);
                    if (j == 0) atomicAdd(&gcnt[g], run);
                    g = sg[nn]; mx = v; sm = v; run = 1;
                } else {
                    mx = fmaxf(mx, v); sm += v; ++run;
                }
            }
            atomicMax(&gmaxk[g * H_DIM + j], fenc(mx));
            atomicAdd(&gsum[g * H_DIM + j], sm);
            if (j == 0) atomicAdd(&gcnt[g], run);
        }
    }
}

// ---------------------------------------------------------------------------
// Head: decode per-graph accumulators -> pooled[96] + linear head.
__global__ __launch_bounds__(256) void head_kernel(const unsigned* __restrict__ gmaxk,
                                                   const float* __restrict__ gsum,
                                                   const int* __restrict__ gcnt,
                                                   const float* __restrict__ Wout,
                                                   const float* __restrict__ bout,
                                                   float* __restrict__ out) {
    __shared__ float sWo[3 * H_DIM];
    int b = threadIdx.x;                   // one thread per graph, 256 threads
    if (b < 3 * H_DIM) sWo[b] = Wout[b];
    __syncthreads();
    float cnt = fmaxf((float)gcnt[b], 1.0f);
    float acc = 0.f;
    float* po = out + B_GRAPHS + (size_t)b * 96;
#pragma unroll
    for (int j = 0; j < H_DIM; ++j) {
        float mx = fdec(gmaxk[b * H_DIM + j]);
        float sm = gsum[b * H_DIM + j];
        float mean = sm / cnt;
        po[j]      = mx;
        po[32 + j] = mean;
        po[64 + j] = sm;
        acc += mx * sWo[j] + mean * sWo[32 + j] + sm * sWo[64 + j];
    }
    out[b] = acc + bout[0];
}

// ---------------------------------------------------------------------------
extern "C" void kernel_launch(void* const* d_in, const int* in_sizes, int n_in,
                              void* d_out, int out_size, void* d_ws, size_t ws_size,
                              hipStream_t stream) {
    const float* x     = (const float*)d_in[0];
    const int*   ei    = (const int*)  d_in[1];   // src = ei[0:E], dst = ei[E:2E]
    const int*   batch = (const int*)  d_in[2];
    const float* W0    = (const float*)d_in[3];
    const float* b0    = (const float*)d_in[4];
    const float* W1    = (const float*)d_in[5];
    const float* b1    = (const float*)d_in[6];
    const float* W2    = (const float*)d_in[7];
    const float* b2    = (const float*)d_in[8];
    const float* W3    = (const float*)d_in[9];
    const float* b3    = (const float*)d_in[10];
    const float* Wout  = (const float*)d_in[11];
    const float* bout  = (const float*)d_in[12];
    float* out = (float*)d_out;

    char* p = (char*)d_ws;
    float*    dinv       = (float*)p;    p += (size_t)N_NODES * 4;            // 16B-mult
    unsigned* hA         = (unsigned*)p; p += (size_t)N_NODES * 16 * 4;
    unsigned* rec        = (unsigned*)p; p += (size_t)NBUCKET * CAPB * 4;     // 8 MB, reused as hB
    int2*     csr        = (int2*)p;     p += (size_t)TPAD * 8;               // 18.4 MB
    int2*     row_meta   = (int2*)p;     p += (size_t)N_NODES * 8;
    int*      bucket_cur = (int*)p;      p += (size_t)NBUCKET * CURSTR * 4;
    unsigned* gmaxk      = (unsigned*)p; p += (size_t)B_GRAPHS * H_DIM * 4;
    float*    gsumA      = (float*)p;    p += (size_t)B_GRAPHS * H_DIM * 4;
    int*      gcnt       = (int*)p;      p += (size_t)B_GRAPHS * 4;
    unsigned* hB = rec;   // alias: rec dead once passC completes

    // ---- edge build: fixed-stride buckets -> per-bucket node sort -> CSR ----
    init_kernel<<<(N_NODES + 255) / 256, 256, 0, stream>>>(bucket_cur, gmaxk, gsumA, gcnt);
    passB_kernel<<<NCHUNK, 1024, 0, stream>>>(ei, bucket_cur, rec);
    dinv_kernel<<<NBUCKET, 256, 0, stream>>>(rec, bucket_cur, dinv);
    passC_kernel<<<NBUCKET, 256, 0, stream>>>(rec, bucket_cur, dinv, row_meta, csr);

    // ---- 4 GCN layers (gather, no atomics, int4 csr, 8 lanes/node) ----
    layer_kernel<F_IN, false, false><<<LAYER_BLOCKS, 256, 0, stream>>>(
        x,  row_meta, (const int4*)csr, dinv, W0, b0, hA, nullptr, nullptr, nullptr, nullptr);
    layer_kernel<H_DIM, true, false><<<LAYER_BLOCKS, 256, 0, stream>>>(
        hA, row_meta, (const int4*)csr, dinv, W1, b1, hB, nullptr, nullptr, nullptr, nullptr);
    layer_kernel<H_DIM, true, false><<<LAYER_BLOCKS, 256, 0, stream>>>(
        hB, row_meta, (const int4*)csr, dinv, W2, b2, hA, nullptr, nullptr, nullptr, nullptr);
    // layer 4: fused pooling (no h store, no pool kernel re-read)
    layer_kernel<H_DIM, true, true><<<LAYER_BLOCKS, 256, 0, stream>>>(
        hA, row_meta, (const int4*)csr, dinv, W3, b3, hB, batch, gmaxk, gsumA, gcnt);

    head_kernel<<<1, 256, 0, stream>>>(gmaxk, gsumA, gcnt, Wout, bout, out);
}

// Round 5
// 309.440 us; speedup vs baseline: 1.0511x; 1.0511x over previous
//
#include <hip/hip_runtime.h>
#include <math.h>

#define N_NODES 100000
#define N_EDGES 1600000
#define F_IN    16
#define H_DIM   32
#define B_GRAPHS 256

#define BSHIFT  7
#define BSIZE   128                                   // nodes per bucket
#define NBUCKET ((N_NODES + BSIZE - 1) / BSIZE)       // 782
#define EPB     8192                                  // edges per chunk block
#define NCHUNK  ((N_EDGES + EPB - 1) / EPB)           // 196
#define CAPB    2560                                  // fixed bucket stride (mean 2048, +11 sigma)
#define CSTRIDE 2944                                  // csr entries reserved per bucket (2560+384)
#define TPAD    (NBUCKET * CSTRIDE)
#define CURSTR  16                                    // bucket_cur stride: 1 counter / 64B line
#define NPB     32                                    // nodes per layer block (8 lanes/node)
#define LAYER_BLOCKS (N_NODES / NPB)                  // 3125

// ---------------------------------------------------------------------------
__device__ inline float bf_lo(unsigned u) { return __uint_as_float(u << 16); }
__device__ inline float bf_hi(unsigned u) { return __uint_as_float(u & 0xffff0000u); }
__device__ inline unsigned pack_bf16x2(float a, float b) {
    unsigned ua = __float_as_uint(a), ub = __float_as_uint(b);
    ua += 0x7fffu + ((ua >> 16) & 1u);    // RNE
    ub += 0x7fffu + ((ub >> 16) & 1u);
    return (ua >> 16) | (ub & 0xffff0000u);
}
// monotone float<->uint for atomicMax on floats (no NaN inputs: tanh outputs)
__device__ inline unsigned fenc(float f) {
    unsigned u = __float_as_uint(f);
    return (u & 0x80000000u) ? ~u : (u | 0x80000000u);
}
__device__ inline float fdec(unsigned k) {
    if (k == 0u) return -INFINITY;        // empty segment sentinel
    return __uint_as_float((k & 0x80000000u) ? (k ^ 0x80000000u) : ~k);
}

// ---------------------------------------------------------------------------
// Init: bucket claim counters + pooling accumulators.
__global__ __launch_bounds__(256) void init_kernel(int* __restrict__ bucket_cur,
                                                   unsigned* __restrict__ gmaxk,
                                                   float* __restrict__ gsum,
                                                   int* __restrict__ gcnt) {
    int t = blockIdx.x * 256 + threadIdx.x;
    if (t < NBUCKET) bucket_cur[t * CURSTR] = t * CAPB;
    if (t < B_GRAPHS * H_DIM) { gmaxk[t] = 0u; gsum[t] = 0.f; }
    if (t < B_GRAPHS) gcnt[t] = 0;
}

// Pass B: per-block histogram -> claim per-bucket runs -> direct scattered
// writes. Record = src | dst_local<<20.
__global__ __launch_bounds__(1024) void passB_kernel(const int* __restrict__ ei,
                                                     int* __restrict__ bucket_cur,
                                                     unsigned* __restrict__ rec_out) {
    __shared__ int hist[NBUCKET];
    __shared__ int gcur[NBUCKET];
    int t = threadIdx.x;
    for (int k = t; k < NBUCKET; k += 1024) hist[k] = 0;
    __syncthreads();

    const int* dst = ei + N_EDGES;
    int base = blockIdx.x * EPB;
    int end  = base + EPB; if (end > N_EDGES) end = N_EDGES;

    for (int e = base + t; e < end; e += 1024) atomicAdd(&hist[dst[e] >> BSHIFT], 1);
    __syncthreads();

    for (int k = t; k < NBUCKET; k += 1024) {
        int h = hist[k];
        gcur[k] = h ? atomicAdd(&bucket_cur[k * CURSTR], h) : 0;
    }
    __syncthreads();

    for (int e = base + t; e < end; e += 1024) {
        int d = dst[e], s = ei[e];
        int bk = d >> BSHIFT;
        int pos = atomicAdd(&gcur[bk], 1);
        rec_out[pos] = (unsigned)s | ((unsigned)(d & (BSIZE - 1)) << 20);
    }
}

// Per-bucket in-degree -> dinv (LDS atomics over the bucket's rec run).
__global__ __launch_bounds__(256) void dinv_kernel(const unsigned* __restrict__ rec,
                                                   const int* __restrict__ bucket_cur,
                                                   float* __restrict__ dinv) {
    __shared__ int cnt[BSIZE];
    int t = threadIdx.x, b = blockIdx.x;
    if (t < BSIZE) cnt[t] = 0;
    __syncthreads();
    int e1 = bucket_cur[b * CURSTR];
    for (int e = b * CAPB + t; e < e1; e += 256) atomicAdd(&cnt[rec[e] >> 20], 1);
    __syncthreads();
    int nd = (b << BSHIFT) + t;
    if (t < BSIZE && nd < N_NODES) dinv[nd] = rsqrtf((float)cnt[t] + 1.0f);
}

// Pass C: per-bucket node sort into padded interleaved CSR: entry=(src,coef).
// Rows padded to multiples of 4; dummy entries use the row's OWN node as src
// (coef=0). row_meta=(start,padded_len).
__global__ __launch_bounds__(256) void passC_kernel(const unsigned* __restrict__ rec,
                                                    const int* __restrict__ bucket_cur,
                                                    const float* __restrict__ dinv,
                                                    int2* __restrict__ row_meta,
                                                    int2* __restrict__ csr) {
    __shared__ unsigned stage[CAPB];
    __shared__ int cnt[BSIZE];
    __shared__ int pds[BSIZE];
    __shared__ int cur[BSIZE];
    __shared__ float sdv[BSIZE];
    int t = threadIdx.x, b = blockIdx.x;
    int node0 = b << BSHIFT;
    int e0 = b * CAPB;
    int n = bucket_cur[b * CURSTR] - e0;
    int pbase = b * CSTRIDE;              // 8-aligned (CSTRIDE % 8 == 0)
    if (t < BSIZE) {
        cnt[t] = 0;
        int nd = node0 + t;
        sdv[t] = (nd < N_NODES) ? dinv[nd] : 0.f;
    }
    __syncthreads();
    for (int k = t; k < n; k += 256) {
        unsigned r = rec[e0 + k];
        stage[k] = r;
        atomicAdd(&cnt[r >> 20], 1);
    }
    __syncthreads();
    // inclusive scan of pad-4 counts
    int pd = 0;
    if (t < BSIZE) { pd = (cnt[t] + 3) & ~3; pds[t] = pd; }
    __syncthreads();
    for (int off = 1; off < BSIZE; off <<= 1) {
        int v = (t < BSIZE && t >= off) ? pds[t - off] : 0;
        __syncthreads();
        if (t < BSIZE) pds[t] += v;
        __syncthreads();
    }
    if (t < BSIZE) {
        int startp = pbase + pds[t] - pd;
        cur[t] = startp;
        int nd = node0 + t;
        if (nd < N_NODES) {
            row_meta[nd] = make_int2(startp, pd);
            for (int k = startp + cnt[t]; k < startp + pd; ++k)
                csr[k] = make_int2(nd, 0);   // dummy: own node, coef 0
        }
    }
    __syncthreads();
    for (int k = t; k < n; k += 256) {
        unsigned r = stage[k];
        int dl = r >> 20;
        int s  = r & 0xFFFFF;
        int pos = atomicAdd(&cur[dl], 1);
        csr[pos] = make_int2(s, __float_as_int(dinv[s] * sdv[dl]));
    }
}

// ---------------------------------------------------------------------------
// GCN layer, 8 lanes/node with TRANSIENT csr: csr int4s are loaded, their
// srcs consumed for gather addresses, and the regs die; at consume time the
// csr line is reloaded from L1 for the coefs (asm clobber on the index
// defeats CSE so the compiler doesn't keep the first loads alive). This
// keeps 16 uint2 gathers (128 edges/wave) in flight at ~56 VGPR — below the
// 64-VGPR occupancy cliff that sank the held-ca variant (88 VGPR, 14.5% occ).
template <int FIN, bool PACKED, bool POOL>
__global__ __launch_bounds__(256) void layer_kernel(
        const void* __restrict__ h_in_v,
        const int2* __restrict__ row_meta,
        const int4* __restrict__ csr4,     // 2 edges per int4
        const float* __restrict__ dinv,
        const float* __restrict__ W,       // [FIN][32]
        const float* __restrict__ bias,    // [32]
        unsigned* __restrict__ h_out,
        const int* __restrict__ batch,
        unsigned* __restrict__ gmaxk,
        float* __restrict__ gsum,
        int* __restrict__ gcnt) {
    constexpr int STR = FIN + 1;
    __shared__ float sW[FIN * H_DIM];
    __shared__ float sb[H_DIM];
    __shared__ float agg[NPB][STR];
    __shared__ int sg[NPB];
    int t = threadIdx.x;
    for (int k = t; k < FIN * H_DIM; k += 256) sW[k] = W[k];
    if (t < H_DIM) sb[t] = bias[t];

    int nl = t >> 3, ln = t & 7;          // 32 nodes/block, 8 lanes/node
    int d0 = 2 * ln;                      // lane's dword pair within a row
    int i = blockIdx.x * NPB + nl;
    int2 m = row_meta[i];
    float di = dinv[i], di2 = di * di;
    int q    = m.x >> 1;                  // int4 index of row start
    int qend = (m.x + m.y) >> 1;

    if (PACKED) {
        const unsigned* hp = (const unsigned*)h_in_v;
        uint2 su = *(const uint2*)(hp + i * 16 + d0);
        float a0 = bf_lo(su.x) * di2, a1 = bf_hi(su.x) * di2;
        float a2 = bf_lo(su.y) * di2, a3 = bf_hi(su.y) * di2;
        for (; q + 8 <= qend; q += 8) {     // 16 edges, transient csr
            uint2 v[16];
            int qq = q;
#pragma unroll
            for (int k = 0; k < 8; ++k) {   // phase 1: srcs -> issue gathers
                int4 c = csr4[qq + k];
                v[2 * k]     = *(const uint2*)(hp + c.x * 16 + d0);
                v[2 * k + 1] = *(const uint2*)(hp + c.z * 16 + d0);
            }
            asm volatile("" : "+v"(qq));    // opaque index: no CSE of csr loads
#pragma unroll
            for (int k = 0; k < 8; ++k) {   // phase 2: coefs (L1 hit) -> FMA
                int4 c = csr4[qq + k];
                float c0 = __int_as_float(c.y), c1 = __int_as_float(c.w);
                a0 += bf_lo(v[2 * k].x) * c0 + bf_lo(v[2 * k + 1].x) * c1;
                a1 += bf_hi(v[2 * k].x) * c0 + bf_hi(v[2 * k + 1].x) * c1;
                a2 += bf_lo(v[2 * k].y) * c0 + bf_lo(v[2 * k + 1].y) * c1;
                a3 += bf_hi(v[2 * k].y) * c0 + bf_hi(v[2 * k + 1].y) * c1;
            }
        }
        if (q + 4 <= qend) {                // 8-edge tail (held csr, small)
            int4 ca[4];
#pragma unroll
            for (int k = 0; k < 4; ++k) ca[k] = csr4[q + k];
#pragma unroll
            for (int k = 0; k < 4; ++k) {
                uint2 v0 = *(const uint2*)(hp + ca[k].x * 16 + d0);
                uint2 v1 = *(const uint2*)(hp + ca[k].z * 16 + d0);
                float c0 = __int_as_float(ca[k].y), c1 = __int_as_float(ca[k].w);
                a0 += bf_lo(v0.x) * c0 + bf_lo(v1.x) * c1;
                a1 += bf_hi(v0.x) * c0 + bf_hi(v1.x) * c1;
                a2 += bf_lo(v0.y) * c0 + bf_lo(v1.y) * c1;
                a3 += bf_hi(v0.y) * c0 + bf_hi(v1.y) * c1;
            }
            q += 4;
        }
        if (q < qend) {                     // 4-edge tail (2 int4s)
            int4 a = csr4[q], b = csr4[q + 1];
            uint2 v0 = *(const uint2*)(hp + a.x * 16 + d0);
            uint2 v1 = *(const uint2*)(hp + a.z * 16 + d0);
            uint2 v2 = *(const uint2*)(hp + b.x * 16 + d0);
            uint2 v3 = *(const uint2*)(hp + b.z * 16 + d0);
            float c0 = __int_as_float(a.y), c1 = __int_as_float(a.w);
            float c2 = __int_as_float(b.y), c3 = __int_as_float(b.w);
            a0 += bf_lo(v0.x) * c0 + bf_lo(v1.x) * c1 + bf_lo(v2.x) * c2 + bf_lo(v3.x) * c3;
            a1 += bf_hi(v0.x) * c0 + bf_hi(v1.x) * c1 + bf_hi(v2.x) * c2 + bf_hi(v3.x) * c3;
            a2 += bf_lo(v0.y) * c0 + bf_lo(v1.y) * c1 + bf_lo(v2.y) * c2 + bf_lo(v3.y) * c3;
            a3 += bf_hi(v0.y) * c0 + bf_hi(v1.y) * c1 + bf_hi(v2.y) * c2 + bf_hi(v3.y) * c3;
        }
        agg[nl][4 * ln]     = a0;          // features 4*ln .. 4*ln+3
        agg[nl][4 * ln + 1] = a1;
        agg[nl][4 * ln + 2] = a2;
        agg[nl][4 * ln + 3] = a3;
    } else {
        const float* xf = (const float*)h_in_v;
        float2 sx = *(const float2*)(xf + i * F_IN + d0);
        float a0 = sx.x * di2, a1 = sx.y * di2;
        for (; q + 8 <= qend; q += 8) {     // 16 edges, transient csr
            float2 v[16];
            int qq = q;
#pragma unroll
            for (int k = 0; k < 8; ++k) {
                int4 c = csr4[qq + k];
                v[2 * k]     = *(const float2*)(xf + c.x * F_IN + d0);
                v[2 * k + 1] = *(const float2*)(xf + c.z * F_IN + d0);
            }
            asm volatile("" : "+v"(qq));
#pragma unroll
            for (int k = 0; k < 8; ++k) {
                int4 c = csr4[qq + k];
                float c0 = __int_as_float(c.y), c1 = __int_as_float(c.w);
                a0 += v[2 * k].x * c0 + v[2 * k + 1].x * c1;
                a1 += v[2 * k].y * c0 + v[2 * k + 1].y * c1;
            }
        }
        if (q + 4 <= qend) {
            int4 ca[4];
#pragma unroll
            for (int k = 0; k < 4; ++k) ca[k] = csr4[q + k];
#pragma unroll
            for (int k = 0; k < 4; ++k) {
                float2 v0 = *(const float2*)(xf + ca[k].x * F_IN + d0);
                float2 v1 = *(const float2*)(xf + ca[k].z * F_IN + d0);
                float c0 = __int_as_float(ca[k].y), c1 = __int_as_float(ca[k].w);
                a0 += v0.x * c0 + v1.x * c1;
                a1 += v0.y * c0 + v1.y * c1;
            }
            q += 4;
        }
        if (q < qend) {
            int4 a = csr4[q], b = csr4[q + 1];
            float2 v0 = *(const float2*)(xf + a.x * F_IN + d0);
            float2 v1 = *(const float2*)(xf + a.z * F_IN + d0);
            float2 v2 = *(const float2*)(xf + b.x * F_IN + d0);
            float2 v3 = *(const float2*)(xf + b.z * F_IN + d0);
            a0 += v0.x * __int_as_float(a.y) + v1.x * __int_as_float(a.w)
                + v2.x * __int_as_float(b.y) + v3.x * __int_as_float(b.w);
            a1 += v0.y * __int_as_float(a.y) + v1.y * __int_as_float(a.w)
                + v2.y * __int_as_float(b.y) + v3.y * __int_as_float(b.w);
        }
        agg[nl][d0]     = a0;              // features 2*ln, 2*ln+1
        agg[nl][d0 + 1] = a1;
    }
    __syncthreads();

    // transform + bias + tanh  (32 nodes x 8 lanes x 4 outputs)
    int j0 = 4 * ln;
    float o0 = sb[j0], o1 = sb[j0 + 1], o2 = sb[j0 + 2], o3 = sb[j0 + 3];
    const float* arow = &agg[nl][0];
#pragma unroll
    for (int k = 0; k < FIN; ++k) {
        float a = arow[k];
        o0 += a * sW[k * H_DIM + j0];
        o1 += a * sW[k * H_DIM + j0 + 1];
        o2 += a * sW[k * H_DIM + j0 + 2];
        o3 += a * sW[k * H_DIM + j0 + 3];
    }
    float t0 = tanhf(o0), t1 = tanhf(o1), t2 = tanhf(o2), t3 = tanhf(o3);

    if (!POOL) {
        uint2 pk;
        pk.x = pack_bf16x2(t0, t1);
        pk.y = pack_bf16x2(t2, t3);
        *(uint2*)(h_out + i * 16 + d0) = pk;
    } else {
        __syncthreads();                   // all agg reads done before reuse
        agg[nl][j0]     = t0;              // stage h values [node][feat]
        agg[nl][j0 + 1] = t1;
        agg[nl][j0 + 2] = t2;
        agg[nl][j0 + 3] = t3;
        if (t < NPB) sg[t] = batch[blockIdx.x * NPB + t];
        __syncthreads();
        if (t < H_DIM) {                   // segmented reduce over 32 sorted nodes
            int j = t;
            int g = sg[0];
            float mx = agg[0][j], sm = mx;
            int run = 1;
            for (int nn = 1; nn < NPB; ++nn) {
                float v = agg[nn][j];
                if (sg[nn] != g) {
                    atomicMax(&gmaxk[g * H_DIM + j], fenc(mx));
                    atomicAdd(&gsum[g * H_DIM + j], sm);
                    if (j == 0) atomicAdd(&gcnt[g], run);
                    g = sg[nn]; mx = v; sm = v; run = 1;
                } else {
                    mx = fmaxf(mx, v); sm += v; ++run;
                }
            }
            atomicMax(&gmaxk[g * H_DIM + j], fenc(mx));
            atomicAdd(&gsum[g * H_DIM + j], sm);
            if (j == 0) atomicAdd(&gcnt[g], run);
        }
    }
}

// ---------------------------------------------------------------------------
// Head: decode per-graph accumulators -> pooled[96] + linear head.
__global__ __launch_bounds__(256) void head_kernel(const unsigned* __restrict__ gmaxk,
                                                   const float* __restrict__ gsum,
                                                   const int* __restrict__ gcnt,
                                                   const float* __restrict__ Wout,
                                                   const float* __restrict__ bout,
                                                   float* __restrict__ out) {
    __shared__ float sWo[3 * H_DIM];
    int b = threadIdx.x;                   // one thread per graph, 256 threads
    if (b < 3 * H_DIM) sWo[b] = Wout[b];
    __syncthreads();
    float cnt = fmaxf((float)gcnt[b], 1.0f);
    float acc = 0.f;
    float* po = out + B_GRAPHS + (size_t)b * 96;
#pragma unroll
    for (int j = 0; j < H_DIM; ++j) {
        float mx = fdec(gmaxk[b * H_DIM + j]);
        float sm = gsum[b * H_DIM + j];
        float mean = sm / cnt;
        po[j]      = mx;
        po[32 + j] = mean;
        po[64 + j] = sm;
        acc += mx * sWo[j] + mean * sWo[32 + j] + sm * sWo[64 + j];
    }
    out[b] = acc + bout[0];
}

// ---------------------------------------------------------------------------
extern "C" void kernel_launch(void* const* d_in, const int* in_sizes, int n_in,
                              void* d_out, int out_size, void* d_ws, size_t ws_size,
                              hipStream_t stream) {
    const float* x     = (const float*)d_in[0];
    const int*   ei    = (const int*)  d_in[1];   // src = ei[0:E], dst = ei[E:2E]
    const int*   batch = (const int*)  d_in[2];
    const float* W0    = (const float*)d_in[3];
    const float* b0    = (const float*)d_in[4];
    const float* W1    = (const float*)d_in[5];
    const float* b1    = (const float*)d_in[6];
    const float* W2    = (const float*)d_in[7];
    const float* b2    = (const float*)d_in[8];
    const float* W3    = (const float*)d_in[9];
    const float* b3    = (const float*)d_in[10];
    const float* Wout  = (const float*)d_in[11];
    const float* bout  = (const float*)d_in[12];
    float* out = (float*)d_out;

    char* p = (char*)d_ws;
    float*    dinv       = (float*)p;    p += (size_t)N_NODES * 4;            // 16B-mult
    unsigned* hA         = (unsigned*)p; p += (size_t)N_NODES * 16 * 4;
    unsigned* rec        = (unsigned*)p; p += (size_t)NBUCKET * CAPB * 4;     // 8 MB, reused as hB
    int2*     csr        = (int2*)p;     p += (size_t)TPAD * 8;               // 18.4 MB
    int2*     row_meta   = (int2*)p;     p += (size_t)N_NODES * 8;
    int*      bucket_cur = (int*)p;      p += (size_t)NBUCKET * CURSTR * 4;
    unsigned* gmaxk      = (unsigned*)p; p += (size_t)B_GRAPHS * H_DIM * 4;
    float*    gsumA      = (float*)p;    p += (size_t)B_GRAPHS * H_DIM * 4;
    int*      gcnt       = (int*)p;      p += (size_t)B_GRAPHS * 4;
    unsigned* hB = rec;   // alias: rec dead once passC completes

    // ---- edge build: fixed-stride buckets -> per-bucket node sort -> CSR ----
    init_kernel<<<(N_NODES + 255) / 256, 256, 0, stream>>>(bucket_cur, gmaxk, gsumA, gcnt);
    passB_kernel<<<NCHUNK, 1024, 0, stream>>>(ei, bucket_cur, rec);
    dinv_kernel<<<NBUCKET, 256, 0, stream>>>(rec, bucket_cur, dinv);
    passC_kernel<<<NBUCKET, 256, 0, stream>>>(rec, bucket_cur, dinv, row_meta, csr);

    // ---- 4 GCN layers (gather, no atomics, transient csr, 8 lanes/node) ----
    layer_kernel<F_IN, false, false><<<LAYER_BLOCKS, 256, 0, stream>>>(
        x,  row_meta, (const int4*)csr, dinv, W0, b0, hA, nullptr, nullptr, nullptr, nullptr);
    layer_kernel<H_DIM, true, false><<<LAYER_BLOCKS, 256, 0, stream>>>(
        hA, row_meta, (const int4*)csr, dinv, W1, b1, hB, nullptr, nullptr, nullptr, nullptr);
    layer_kernel<H_DIM, true, false><<<LAYER_BLOCKS, 256, 0, stream>>>(
        hB, row_meta, (const int4*)csr, dinv, W2, b2, hA, nullptr, nullptr, nullptr, nullptr);
    // layer 4: fused pooling (no h store, no pool kernel re-read)
    layer_kernel<H_DIM, true, true><<<LAYER_BLOCKS, 256, 0, stream>>>(
        hA, row_meta, (const int4*)csr, dinv, W3, b3, hB, batch, gmaxk, gsumA, gcnt);

    head_kernel<<<1, 256, 0, stream>>>(gmaxk, gsumA, gcnt, Wout, bout, out);
}

// Round 7
// 286.005 us; speedup vs baseline: 1.1372x; 1.0819x over previous
//
#include <hip/hip_runtime.h>
#include <math.h>

#define N_NODES 100000
#define N_EDGES 1600000
#define F_IN    16
#define H_DIM   32
#define B_GRAPHS 256

#define BSHIFT  7
#define BSIZE   128                                   // nodes per bucket
#define NBUCKET ((N_NODES + BSIZE - 1) / BSIZE)       // 782
#define EPB     8192                                  // edges per chunk block
#define NCHUNK  ((N_EDGES + EPB - 1) / EPB)           // 196
#define CAPB    2560                                  // fixed bucket stride (mean 2048, +11 sigma)
#define CSTRIDE 2944                                  // csr entries reserved per bucket (2560+384)
#define TPAD    (NBUCKET * CSTRIDE)
#define CURSTR  16                                    // bucket_cur stride: 1 counter / 64B line
#define NPB     16                                    // nodes per layer block (16 lanes/node)
#define LAYER_BLOCKS (N_NODES / NPB)                  // 6250

// ---------------------------------------------------------------------------
__device__ inline float bf_lo(unsigned u) { return __uint_as_float(u << 16); }
__device__ inline float bf_hi(unsigned u) { return __uint_as_float(u & 0xffff0000u); }
__device__ inline unsigned pack_bf16x2(float a, float b) {
    unsigned ua = __float_as_uint(a), ub = __float_as_uint(b);
    ua += 0x7fffu + ((ua >> 16) & 1u);    // RNE
    ub += 0x7fffu + ((ub >> 16) & 1u);
    return (ua >> 16) | (ub & 0xffff0000u);
}
// monotone float<->uint for atomicMax on floats (no NaN inputs: tanh outputs)
__device__ inline unsigned fenc(float f) {
    unsigned u = __float_as_uint(f);
    return (u & 0x80000000u) ? ~u : (u | 0x80000000u);
}
__device__ inline float fdec(unsigned k) {
    if (k == 0u) return -INFINITY;        // empty segment sentinel
    return __uint_as_float((k & 0x80000000u) ? (k ^ 0x80000000u) : ~k);
}
// async global->LDS, 4B per lane; global src addr is PER-LANE, LDS dest is
// wave-uniform base + lane*4 (guide §5 / m173). In-flight data lives in LDS,
// not VGPRs -> breaks the ILP<->occupancy register catch-22 of r2/r4/r5.
__device__ inline void gld_lds4(const unsigned* g, unsigned* l) {
    __builtin_amdgcn_global_load_lds(
        (const __attribute__((address_space(1))) unsigned*)g,
        (__attribute__((address_space(3))) unsigned*)l, 4, 0, 0);
}

// ---------------------------------------------------------------------------
// Init: bucket claim counters + pooling accumulators.
__global__ __launch_bounds__(256) void init_kernel(int* __restrict__ bucket_cur,
                                                   unsigned* __restrict__ gmaxk,
                                                   float* __restrict__ gsum,
                                                   int* __restrict__ gcnt) {
    int t = blockIdx.x * 256 + threadIdx.x;
    if (t < NBUCKET) bucket_cur[t * CURSTR] = t * CAPB;
    if (t < B_GRAPHS * H_DIM) { gmaxk[t] = 0u; gsum[t] = 0.f; }
    if (t < B_GRAPHS) gcnt[t] = 0;
}

// Pass B: per-block histogram -> claim per-bucket runs -> direct scattered
// writes. Record = src | dst_local<<20.
__global__ __launch_bounds__(1024) void passB_kernel(const int* __restrict__ ei,
                                                     int* __restrict__ bucket_cur,
                                                     unsigned* __restrict__ rec_out) {
    __shared__ int hist[NBUCKET];
    __shared__ int gcur[NBUCKET];
    int t = threadIdx.x;
    for (int k = t; k < NBUCKET; k += 1024) hist[k] = 0;
    __syncthreads();

    const int* dst = ei + N_EDGES;
    int base = blockIdx.x * EPB;
    int end  = base + EPB; if (end > N_EDGES) end = N_EDGES;

    for (int e = base + t; e < end; e += 1024) atomicAdd(&hist[dst[e] >> BSHIFT], 1);
    __syncthreads();

    for (int k = t; k < NBUCKET; k += 1024) {
        int h = hist[k];
        gcur[k] = h ? atomicAdd(&bucket_cur[k * CURSTR], h) : 0;
    }
    __syncthreads();

    for (int e = base + t; e < end; e += 1024) {
        int d = dst[e], s = ei[e];
        int bk = d >> BSHIFT;
        int pos = atomicAdd(&gcur[bk], 1);
        rec_out[pos] = (unsigned)s | ((unsigned)(d & (BSIZE - 1)) << 20);
    }
}

// Per-bucket in-degree -> dinv (LDS atomics over the bucket's rec run).
__global__ __launch_bounds__(256) void dinv_kernel(const unsigned* __restrict__ rec,
                                                   const int* __restrict__ bucket_cur,
                                                   float* __restrict__ dinv) {
    __shared__ int cnt[BSIZE];
    int t = threadIdx.x, b = blockIdx.x;
    if (t < BSIZE) cnt[t] = 0;
    __syncthreads();
    int e1 = bucket_cur[b * CURSTR];
    for (int e = b * CAPB + t; e < e1; e += 256) atomicAdd(&cnt[rec[e] >> 20], 1);
    __syncthreads();
    int nd = (b << BSHIFT) + t;
    if (t < BSIZE && nd < N_NODES) dinv[nd] = rsqrtf((float)cnt[t] + 1.0f);
}

// Pass C: per-bucket node sort into padded interleaved CSR: entry=(src,coef).
// Rows padded to multiples of 4; dummy entries use the row's OWN node as src
// (coef=0). row_meta=(start,padded_len).
__global__ __launch_bounds__(256) void passC_kernel(const unsigned* __restrict__ rec,
                                                    const int* __restrict__ bucket_cur,
                                                    const float* __restrict__ dinv,
                                                    int2* __restrict__ row_meta,
                                                    int2* __restrict__ csr) {
    __shared__ unsigned stage[CAPB];
    __shared__ int cnt[BSIZE];
    __shared__ int pds[BSIZE];
    __shared__ int cur[BSIZE];
    __shared__ float sdv[BSIZE];
    int t = threadIdx.x, b = blockIdx.x;
    int node0 = b << BSHIFT;
    int e0 = b * CAPB;
    int n = bucket_cur[b * CURSTR] - e0;
    int pbase = b * CSTRIDE;              // 8-aligned (CSTRIDE % 8 == 0)
    if (t < BSIZE) {
        cnt[t] = 0;
        int nd = node0 + t;
        sdv[t] = (nd < N_NODES) ? dinv[nd] : 0.f;
    }
    __syncthreads();
    for (int k = t; k < n; k += 256) {
        unsigned r = rec[e0 + k];
        stage[k] = r;
        atomicAdd(&cnt[r >> 20], 1);
    }
    __syncthreads();
    // inclusive scan of pad-4 counts
    int pd = 0;
    if (t < BSIZE) { pd = (cnt[t] + 3) & ~3; pds[t] = pd; }
    __syncthreads();
    for (int off = 1; off < BSIZE; off <<= 1) {
        int v = (t < BSIZE && t >= off) ? pds[t - off] : 0;
        __syncthreads();
        if (t < BSIZE) pds[t] += v;
        __syncthreads();
    }
    if (t < BSIZE) {
        int startp = pbase + pds[t] - pd;
        cur[t] = startp;
        int nd = node0 + t;
        if (nd < N_NODES) {
            row_meta[nd] = make_int2(startp, pd);
            for (int k = startp + cnt[t]; k < startp + pd; ++k)
                csr[k] = make_int2(nd, 0);   // dummy: own node, coef 0
        }
    }
    __syncthreads();
    for (int k = t; k < n; k += 256) {
        unsigned r = stage[k];
        int dl = r >> 20;
        int s  = r & 0xFFFFF;
        int pos = atomicAdd(&cur[dl], 1);
        csr[pos] = make_int2(s, __float_as_int(dinv[s] * sdv[dl]));
    }
}

// ---------------------------------------------------------------------------
// GCN layer, 16 lanes/node, LDS-STAGED gather: per 16-edge chunk, issue 16
// global_load_lds (4B/lane, per-lane scattered src addr) into a per-wave
// private 4KB LDS region; only the 16 coefs stay in registers. vmcnt(0) +
// sched_barrier before consume; lgkmcnt(0) at loop top so the next chunk's
// DMA can't overwrite slots still being ds_read. Rows of h_in are 16 dwords
// for BOTH f32 x (16 floats) and packed h (16 bf16x2) -> unified staging.
template <int FIN, bool PACKED, bool POOL>
__global__ __launch_bounds__(256) void layer_kernel(
        const void* __restrict__ h_in_v,
        const int2* __restrict__ row_meta,
        const int4* __restrict__ csr4,     // 2 edges per int4
        const float* __restrict__ dinv,
        const float* __restrict__ W,       // [FIN][32]
        const float* __restrict__ bias,    // [32]
        unsigned* __restrict__ h_out,
        const int* __restrict__ batch,
        unsigned* __restrict__ gmaxk,
        float* __restrict__ gsum,
        int* __restrict__ gcnt) {
    constexpr int STR = FIN + 1;
    __shared__ float sW[FIN * H_DIM];
    __shared__ float sb[H_DIM];
    __shared__ float agg[NPB][STR];
    __shared__ int sg[NPB];
    __shared__ unsigned stg[4][16][64];    // [wave][edge slot][lane]  16 KB
    int t = threadIdx.x;
    for (int k = t; k < FIN * H_DIM; k += 256) sW[k] = W[k];
    if (t < H_DIM) sb[t] = bias[t];

    int wid = t >> 6, lane = t & 63;
    int nl = t >> 4, ln = t & 15;
    int i = blockIdx.x * NPB + nl;
    int2 m = row_meta[i];
    float di = dinv[i], di2 = di * di;
    int q    = m.x >> 1;                  // int4 index of row start
    int qend = (m.x + m.y) >> 1;

    const unsigned* hp = (const unsigned*)h_in_v;   // 16-dword rows
    unsigned su = hp[i * 16 + ln];
    float a0, a1 = 0.f;
    if (PACKED) { a0 = bf_lo(su) * di2; a1 = bf_hi(su) * di2; }
    else        { a0 = __uint_as_float(su) * di2; }

    unsigned* sl0 = &stg[wid][0][0];
    for (; q + 8 <= qend; q += 8) {       // 16 edges per node, DMA-staged
        asm volatile("s_waitcnt lgkmcnt(0)" ::: "memory");  // prior ds_reads drained
        float cf[16];
#pragma unroll
        for (int k = 0; k < 8; ++k) {
            int4 c = csr4[q + k];
            gld_lds4(hp + c.x * 16 + ln, sl0 + (2 * k) * 64);
            gld_lds4(hp + c.z * 16 + ln, sl0 + (2 * k + 1) * 64);
            cf[2 * k]     = __int_as_float(c.y);
            cf[2 * k + 1] = __int_as_float(c.w);
        }
        asm volatile("s_waitcnt vmcnt(0)" ::: "memory");
        __builtin_amdgcn_sched_barrier(0);
#pragma unroll
        for (int k = 0; k < 16; ++k) {
            unsigned u = stg[wid][k][lane];
            if (PACKED) { a0 += bf_lo(u) * cf[k]; a1 += bf_hi(u) * cf[k]; }
            else        { a0 += __uint_as_float(u) * cf[k]; }
        }
    }
    if (q + 4 <= qend) {                  // 8-edge register tail
        int4 ca[4];
#pragma unroll
        for (int k = 0; k < 4; ++k) ca[k] = csr4[q + k];
#pragma unroll
        for (int k = 0; k < 4; ++k) {
            unsigned v0 = hp[ca[k].x * 16 + ln], v1 = hp[ca[k].z * 16 + ln];
            float c0 = __int_as_float(ca[k].y), c1 = __int_as_float(ca[k].w);
            if (PACKED) {
                a0 += bf_lo(v0) * c0 + bf_lo(v1) * c1;
                a1 += bf_hi(v0) * c0 + bf_hi(v1) * c1;
            } else {
                a0 += __uint_as_float(v0) * c0 + __uint_as_float(v1) * c1;
            }
        }
        q += 4;
    }
    if (q < qend) {                       // 4-edge tail (2 int4s)
        int4 a = csr4[q], b = csr4[q + 1];
        unsigned v0 = hp[a.x * 16 + ln], v1 = hp[a.z * 16 + ln];
        unsigned v2 = hp[b.x * 16 + ln], v3 = hp[b.z * 16 + ln];
        float c0 = __int_as_float(a.y), c1 = __int_as_float(a.w);
        float c2 = __int_as_float(b.y), c3 = __int_as_float(b.w);
        if (PACKED) {
            a0 += bf_lo(v0) * c0 + bf_lo(v1) * c1 + bf_lo(v2) * c2 + bf_lo(v3) * c3;
            a1 += bf_hi(v0) * c0 + bf_hi(v1) * c1 + bf_hi(v2) * c2 + bf_hi(v3) * c3;
        } else {
            a0 += __uint_as_float(v0) * c0 + __uint_as_float(v1) * c1
                + __uint_as_float(v2) * c2 + __uint_as_float(v3) * c3;
        }
    }
    if (PACKED) { agg[nl][2 * ln] = a0; agg[nl][2 * ln + 1] = a1; }
    else        { agg[nl][ln] = a0; }
    __syncthreads();

    // transform + bias + tanh  (16 nodes x 16 feat-pairs)
    int j0 = 2 * ln;
    float o0 = sb[j0], o1 = sb[j0 + 1];
    const float* arow = &agg[nl][0];
#pragma unroll
    for (int k = 0; k < FIN; ++k) {
        float a = arow[k];
        o0 += a * sW[k * H_DIM + j0];
        o1 += a * sW[k * H_DIM + j0 + 1];
    }
    float t0 = tanhf(o0), t1 = tanhf(o1);

    if (!POOL) {
        h_out[i * 16 + ln] = pack_bf16x2(t0, t1);
    } else {
        __syncthreads();                   // all agg reads done before reuse
        agg[nl][j0]     = t0;              // stage h values [node][feat]
        agg[nl][j0 + 1] = t1;
        if (t < NPB) sg[t] = batch[blockIdx.x * NPB + t];
        __syncthreads();
        if (t < H_DIM) {                   // segmented reduce over 16 sorted nodes
            int j = t;
            int g = sg[0];
            float mx = agg[0][j], sm = mx;
            int run = 1;
            for (int nn = 1; nn < NPB; ++nn) {
                float v = agg[nn][j];
                if (sg[nn] != g) {
                    atomicMax(&gmaxk[g * H_DIM + j], fenc(mx));
                    atomicAdd(&gsum[g * H_DIM + j], sm);
                    if (j == 0) atomicAdd(&gcnt[g], run);
                    g = sg[nn]; mx = v; sm = v; run = 1;
                } else {
                    mx = fmaxf(mx, v); sm += v; ++run;
                }
            }
            atomicMax(&gmaxk[g * H_DIM + j], fenc(mx));
            atomicAdd(&gsum[g * H_DIM + j], sm);
            if (j == 0) atomicAdd(&gcnt[g], run);
        }
    }
}

// ---------------------------------------------------------------------------
// Head: decode per-graph accumulators -> pooled[96] + linear head.
__global__ __launch_bounds__(256) void head_kernel(const unsigned* __restrict__ gmaxk,
                                                   const float* __restrict__ gsum,
                                                   const int* __restrict__ gcnt,
                                                   const float* __restrict__ Wout,
                                                   const float* __restrict__ bout,
                                                   float* __restrict__ out) {
    __shared__ float sWo[3 * H_DIM];
    int b = threadIdx.x;                   // one thread per graph, 256 threads
    if (b < 3 * H_DIM) sWo[b] = Wout[b];
    __syncthreads();
    float cnt = fmaxf((float)gcnt[b], 1.0f);
    float acc = 0.f;
    float* po = out + B_GRAPHS + (size_t)b * 96;
#pragma unroll
    for (int j = 0; j < H_DIM; ++j) {
        float mx = fdec(gmaxk[b * H_DIM + j]);
        float sm = gsum[b * H_DIM + j];
        float mean = sm / cnt;
        po[j]      = mx;
        po[32 + j] = mean;
        po[64 + j] = sm;
        acc += mx * sWo[j] + mean * sWo[32 + j] + sm * sWo[64 + j];
    }
    out[b] = acc + bout[0];
}

// ---------------------------------------------------------------------------
extern "C" void kernel_launch(void* const* d_in, const int* in_sizes, int n_in,
                              void* d_out, int out_size, void* d_ws, size_t ws_size,
                              hipStream_t stream) {
    const float* x     = (const float*)d_in[0];
    const int*   ei    = (const int*)  d_in[1];   // src = ei[0:E], dst = ei[E:2E]
    const int*   batch = (const int*)  d_in[2];
    const float* W0    = (const float*)d_in[3];
    const float* b0    = (const float*)d_in[4];
    const float* W1    = (const float*)d_in[5];
    const float* b1    = (const float*)d_in[6];
    const float* W2    = (const float*)d_in[7];
    const float* b2    = (const float*)d_in[8];
    const float* W3    = (const float*)d_in[9];
    const float* b3    = (const float*)d_in[10];
    const float* Wout  = (const float*)d_in[11];
    const float* bout  = (const float*)d_in[12];
    float* out = (float*)d_out;

    char* p = (char*)d_ws;
    float*    dinv       = (float*)p;    p += (size_t)N_NODES * 4;            // 16B-mult
    unsigned* hA         = (unsigned*)p; p += (size_t)N_NODES * 16 * 4;
    unsigned* rec        = (unsigned*)p; p += (size_t)NBUCKET * CAPB * 4;     // 8 MB, reused as hB
    int2*     csr        = (int2*)p;     p += (size_t)TPAD * 8;               // 18.4 MB
    int2*     row_meta   = (int2*)p;     p += (size_t)N_NODES * 8;
    int*      bucket_cur = (int*)p;      p += (size_t)NBUCKET * CURSTR * 4;
    unsigned* gmaxk      = (unsigned*)p; p += (size_t)B_GRAPHS * H_DIM * 4;
    float*    gsumA      = (float*)p;    p += (size_t)B_GRAPHS * H_DIM * 4;
    int*      gcnt       = (int*)p;      p += (size_t)B_GRAPHS * 4;
    unsigned* hB = rec;   // alias: rec dead once passC completes

    // ---- edge build: fixed-stride buckets -> per-bucket node sort -> CSR ----
    init_kernel<<<(N_NODES + 255) / 256, 256, 0, stream>>>(bucket_cur, gmaxk, gsumA, gcnt);
    passB_kernel<<<NCHUNK, 1024, 0, stream>>>(ei, bucket_cur, rec);
    dinv_kernel<<<NBUCKET, 256, 0, stream>>>(rec, bucket_cur, dinv);
    passC_kernel<<<NBUCKET, 256, 0, stream>>>(rec, bucket_cur, dinv, row_meta, csr);

    // ---- 4 GCN layers (gather, LDS-staged via global_load_lds) ----
    layer_kernel<F_IN, false, false><<<LAYER_BLOCKS, 256, 0, stream>>>(
        x,  row_meta, (const int4*)csr, dinv, W0, b0, hA, nullptr, nullptr, nullptr, nullptr);
    layer_kernel<H_DIM, true, false><<<LAYER_BLOCKS, 256, 0, stream>>>(
        hA, row_meta, (const int4*)csr, dinv, W1, b1, hB, nullptr, nullptr, nullptr, nullptr);
    layer_kernel<H_DIM, true, false><<<LAYER_BLOCKS, 256, 0, stream>>>(
        hB, row_meta, (const int4*)csr, dinv, W2, b2, hA, nullptr, nullptr, nullptr, nullptr);
    // layer 4: fused pooling (no h store, no pool kernel re-read)
    layer_kernel<H_DIM, true, true><<<LAYER_BLOCKS, 256, 0, stream>>>(
        hA, row_meta, (const int4*)csr, dinv, W3, b3, hB, batch, gmaxk, gsumA, gcnt);

    head_kernel<<<1, 256, 0, stream>>>(gmaxk, gsumA, gcnt, Wout, bout, out);
}

// Round 8
// 269.253 us; speedup vs baseline: 1.2080x; 1.0622x over previous
//
#include <hip/hip_runtime.h>
#include <math.h>

#define N_NODES 100000
#define N_EDGES 1600000
#define F_IN    16
#define H_DIM   32
#define B_GRAPHS 256

#define BSHIFT  7
#define BSIZE   128                                   // nodes per bucket
#define NBUCKET ((N_NODES + BSIZE - 1) / BSIZE)       // 782
#define EPB     8192                                  // edges per chunk block
#define NCHUNK  ((N_EDGES + EPB - 1) / EPB)           // 196
#define CAPB    2560                                  // fixed bucket stride (mean 2048, +11 sigma)
#define CSTRIDE 2944                                  // csr entries reserved per bucket (2560+384)
#define TPAD    (NBUCKET * CSTRIDE)
#define CURSTR  16                                    // bucket_cur stride: 1 counter / 64B line
#define NPB     16                                    // nodes per layer block (16 lanes/node)
#define LAYER_BLOCKS (N_NODES / NPB)                  // 6250

// ---------------------------------------------------------------------------
__device__ inline float bf_lo(unsigned u) { return __uint_as_float(u << 16); }
__device__ inline float bf_hi(unsigned u) { return __uint_as_float(u & 0xffff0000u); }
__device__ inline unsigned pack_bf16x2(float a, float b) {
    unsigned ua = __float_as_uint(a), ub = __float_as_uint(b);
    ua += 0x7fffu + ((ua >> 16) & 1u);    // RNE
    ub += 0x7fffu + ((ub >> 16) & 1u);
    return (ua >> 16) | (ub & 0xffff0000u);
}
// monotone float<->uint for atomicMax on floats (no NaN inputs: tanh outputs)
__device__ inline unsigned fenc(float f) {
    unsigned u = __float_as_uint(f);
    return (u & 0x80000000u) ? ~u : (u | 0x80000000u);
}
__device__ inline float fdec(unsigned k) {
    if (k == 0u) return -INFINITY;        // empty segment sentinel
    return __uint_as_float((k & 0x80000000u) ? (k ^ 0x80000000u) : ~k);
}

// ---------------------------------------------------------------------------
// Init: bucket claim counters + pooling accumulators.
__global__ __launch_bounds__(256) void init_kernel(int* __restrict__ bucket_cur,
                                                   unsigned* __restrict__ gmaxk,
                                                   float* __restrict__ gsum,
                                                   int* __restrict__ gcnt) {
    int t = blockIdx.x * 256 + threadIdx.x;
    if (t < NBUCKET) bucket_cur[t * CURSTR] = t * CAPB;
    if (t < B_GRAPHS * H_DIM) { gmaxk[t] = 0u; gsum[t] = 0.f; }
    if (t < B_GRAPHS) gcnt[t] = 0;
}

// Pass B: per-block histogram -> claim per-bucket runs -> direct scattered
// writes. Record = src | dst_local<<20.
__global__ __launch_bounds__(1024) void passB_kernel(const int* __restrict__ ei,
                                                     int* __restrict__ bucket_cur,
                                                     unsigned* __restrict__ rec_out) {
    __shared__ int hist[NBUCKET];
    __shared__ int gcur[NBUCKET];
    int t = threadIdx.x;
    for (int k = t; k < NBUCKET; k += 1024) hist[k] = 0;
    __syncthreads();

    const int* dst = ei + N_EDGES;
    int base = blockIdx.x * EPB;
    int end  = base + EPB; if (end > N_EDGES) end = N_EDGES;

    for (int e = base + t; e < end; e += 1024) atomicAdd(&hist[dst[e] >> BSHIFT], 1);
    __syncthreads();

    for (int k = t; k < NBUCKET; k += 1024) {
        int h = hist[k];
        gcur[k] = h ? atomicAdd(&bucket_cur[k * CURSTR], h) : 0;
    }
    __syncthreads();

    for (int e = base + t; e < end; e += 1024) {
        int d = dst[e], s = ei[e];
        int bk = d >> BSHIFT;
        int pos = atomicAdd(&gcur[bk], 1);
        rec_out[pos] = (unsigned)s | ((unsigned)(d & (BSIZE - 1)) << 20);
    }
}

// Per-bucket in-degree -> dinv (LDS atomics over the bucket's rec run).
__global__ __launch_bounds__(256) void dinv_kernel(const unsigned* __restrict__ rec,
                                                   const int* __restrict__ bucket_cur,
                                                   float* __restrict__ dinv) {
    __shared__ int cnt[BSIZE];
    int t = threadIdx.x, b = blockIdx.x;
    if (t < BSIZE) cnt[t] = 0;
    __syncthreads();
    int e1 = bucket_cur[b * CURSTR];
    for (int e = b * CAPB + t; e < e1; e += 256) atomicAdd(&cnt[rec[e] >> 20], 1);
    __syncthreads();
    int nd = (b << BSHIFT) + t;
    if (t < BSIZE && nd < N_NODES) dinv[nd] = rsqrtf((float)cnt[t] + 1.0f);
}

// Pass C: per-bucket node sort into padded interleaved CSR: entry=(src,coef).
// Rows padded to multiples of 4; dummy entries use the row's OWN node as src
// (coef=0). row_meta=(start,padded_len).
__global__ __launch_bounds__(256) void passC_kernel(const unsigned* __restrict__ rec,
                                                    const int* __restrict__ bucket_cur,
                                                    const float* __restrict__ dinv,
                                                    int2* __restrict__ row_meta,
                                                    int2* __restrict__ csr) {
    __shared__ unsigned stage[CAPB];
    __shared__ int cnt[BSIZE];
    __shared__ int pds[BSIZE];
    __shared__ int cur[BSIZE];
    __shared__ float sdv[BSIZE];
    int t = threadIdx.x, b = blockIdx.x;
    int node0 = b << BSHIFT;
    int e0 = b * CAPB;
    int n = bucket_cur[b * CURSTR] - e0;
    int pbase = b * CSTRIDE;              // 8-aligned (CSTRIDE % 8 == 0)
    if (t < BSIZE) {
        cnt[t] = 0;
        int nd = node0 + t;
        sdv[t] = (nd < N_NODES) ? dinv[nd] : 0.f;
    }
    __syncthreads();
    for (int k = t; k < n; k += 256) {
        unsigned r = rec[e0 + k];
        stage[k] = r;
        atomicAdd(&cnt[r >> 20], 1);
    }
    __syncthreads();
    // inclusive scan of pad-4 counts
    int pd = 0;
    if (t < BSIZE) { pd = (cnt[t] + 3) & ~3; pds[t] = pd; }
    __syncthreads();
    for (int off = 1; off < BSIZE; off <<= 1) {
        int v = (t < BSIZE && t >= off) ? pds[t - off] : 0;
        __syncthreads();
        if (t < BSIZE) pds[t] += v;
        __syncthreads();
    }
    if (t < BSIZE) {
        int startp = pbase + pds[t] - pd;
        cur[t] = startp;
        int nd = node0 + t;
        if (nd < N_NODES) {
            row_meta[nd] = make_int2(startp, pd);
            for (int k = startp + cnt[t]; k < startp + pd; ++k)
                csr[k] = make_int2(nd, 0);   // dummy: own node, coef 0
        }
    }
    __syncthreads();
    for (int k = t; k < n; k += 256) {
        unsigned r = stage[k];
        int dl = r >> 20;
        int s  = r & 0xFFFFF;
        int pos = atomicAdd(&cur[dl], 1);
        csr[pos] = make_int2(s, __float_as_int(dinv[s] * sdv[dl]));
    }
}

// ---------------------------------------------------------------------------
// GCN layer: gather aggregation, 16-edge main chunks (+8/+4 tails) for deep
// MLP; csr as int4 (2 edges/load), PLAIN loads (nt on csr put the serial
// csr->gather chain on L2 latency: r0<=47us -> r2 56us; reverted). Fused
// W + bias + tanh + bf16x2 pack. POOL variant merges per-graph max/sum/count
// via global atomics (no final h store, no separate pool kernel).
template <int FIN, bool PACKED, bool POOL>
__global__ __launch_bounds__(256) void layer_kernel(
        const void* __restrict__ h_in_v,
        const int2* __restrict__ row_meta,
        const int4* __restrict__ csr4,     // 2 edges per int4
        const float* __restrict__ dinv,
        const float* __restrict__ W,       // [FIN][32]
        const float* __restrict__ bias,    // [32]
        unsigned* __restrict__ h_out,
        const int* __restrict__ batch,
        unsigned* __restrict__ gmaxk,
        float* __restrict__ gsum,
        int* __restrict__ gcnt) {
    constexpr int STR = FIN + 1;
    __shared__ float sW[FIN * H_DIM];
    __shared__ float sb[H_DIM];
    __shared__ float agg[NPB][STR];
    __shared__ int sg[NPB];
    int t = threadIdx.x;
    for (int k = t; k < FIN * H_DIM; k += 256) sW[k] = W[k];
    if (t < H_DIM) sb[t] = bias[t];

    int nl = t >> 4, ln = t & 15;
    int i = blockIdx.x * NPB + nl;
    int2 m = row_meta[i];
    float di = dinv[i], di2 = di * di;
    int q    = m.x >> 1;                // int4 index of row start (16B-aligned)
    int qend = (m.x + m.y) >> 1;

    if (PACKED) {
        const unsigned* hp = (const unsigned*)h_in_v;
        unsigned u = hp[i * 16 + ln];
        float acc0 = bf_lo(u) * di2, acc1 = bf_hi(u) * di2;
        for (; q + 8 <= qend; q += 8) {     // 16 edges in flight
            int4 ca[8];
#pragma unroll
            for (int k = 0; k < 8; ++k) ca[k] = csr4[q + k];
            unsigned v[16];
#pragma unroll
            for (int k = 0; k < 8; ++k) {
                v[2 * k]     = hp[ca[k].x * 16 + ln];
                v[2 * k + 1] = hp[ca[k].z * 16 + ln];
            }
#pragma unroll
            for (int k = 0; k < 8; ++k) {
                float c0 = __int_as_float(ca[k].y), c1 = __int_as_float(ca[k].w);
                acc0 += bf_lo(v[2 * k]) * c0 + bf_lo(v[2 * k + 1]) * c1;
                acc1 += bf_hi(v[2 * k]) * c0 + bf_hi(v[2 * k + 1]) * c1;
            }
        }
        if (q + 4 <= qend) {                // 8-edge tail
            int4 ca[4];
#pragma unroll
            for (int k = 0; k < 4; ++k) ca[k] = csr4[q + k];
#pragma unroll
            for (int k = 0; k < 4; ++k) {
                unsigned v0 = hp[ca[k].x * 16 + ln], v1 = hp[ca[k].z * 16 + ln];
                float c0 = __int_as_float(ca[k].y), c1 = __int_as_float(ca[k].w);
                acc0 += bf_lo(v0) * c0 + bf_lo(v1) * c1;
                acc1 += bf_hi(v0) * c0 + bf_hi(v1) * c1;
            }
            q += 4;
        }
        if (q < qend) {                     // 4-edge tail (2 int4s)
            int4 a = csr4[q], b = csr4[q + 1];
            unsigned v0 = hp[a.x * 16 + ln], v1 = hp[a.z * 16 + ln];
            unsigned v2 = hp[b.x * 16 + ln], v3 = hp[b.z * 16 + ln];
            float c0 = __int_as_float(a.y), c1 = __int_as_float(a.w);
            float c2 = __int_as_float(b.y), c3 = __int_as_float(b.w);
            acc0 += bf_lo(v0) * c0 + bf_lo(v1) * c1 + bf_lo(v2) * c2 + bf_lo(v3) * c3;
            acc1 += bf_hi(v0) * c0 + bf_hi(v1) * c1 + bf_hi(v2) * c2 + bf_hi(v3) * c3;
        }
        agg[nl][2 * ln]     = acc0;
        agg[nl][2 * ln + 1] = acc1;
    } else {
        const float* xf = (const float*)h_in_v;
        float acc = xf[i * F_IN + ln] * di2;
        for (; q + 8 <= qend; q += 8) {
            int4 ca[8];
#pragma unroll
            for (int k = 0; k < 8; ++k) ca[k] = csr4[q + k];
            float v[16];
#pragma unroll
            for (int k = 0; k < 8; ++k) {
                v[2 * k]     = xf[ca[k].x * F_IN + ln];
                v[2 * k + 1] = xf[ca[k].z * F_IN + ln];
            }
#pragma unroll
            for (int k = 0; k < 8; ++k)
                acc += v[2 * k] * __int_as_float(ca[k].y)
                     + v[2 * k + 1] * __int_as_float(ca[k].w);
        }
        if (q + 4 <= qend) {
            int4 ca[4];
#pragma unroll
            for (int k = 0; k < 4; ++k) ca[k] = csr4[q + k];
#pragma unroll
            for (int k = 0; k < 4; ++k)
                acc += xf[ca[k].x * F_IN + ln] * __int_as_float(ca[k].y)
                     + xf[ca[k].z * F_IN + ln] * __int_as_float(ca[k].w);
            q += 4;
        }
        if (q < qend) {
            int4 a = csr4[q], b = csr4[q + 1];
            acc += xf[a.x * F_IN + ln] * __int_as_float(a.y)
                 + xf[a.z * F_IN + ln] * __int_as_float(a.w)
                 + xf[b.x * F_IN + ln] * __int_as_float(b.y)
                 + xf[b.z * F_IN + ln] * __int_as_float(b.w);
        }
        agg[nl][ln] = acc;
    }
    __syncthreads();

    // transform + bias + tanh  (16 nodes x 16 feat-pairs)
    int j0 = 2 * ln;
    float o0 = sb[j0], o1 = sb[j0 + 1];
    const float* arow = &agg[nl][0];
#pragma unroll
    for (int k = 0; k < FIN; ++k) {
        float a = arow[k];
        o0 += a * sW[k * H_DIM + j0];
        o1 += a * sW[k * H_DIM + j0 + 1];
    }
    float t0 = tanhf(o0), t1 = tanhf(o1);

    if (!POOL) {
        h_out[i * 16 + ln] = pack_bf16x2(t0, t1);
    } else {
        __syncthreads();                   // all agg reads done before reuse
        agg[nl][j0]     = t0;              // stage h values [node][feat]
        agg[nl][j0 + 1] = t1;
        if (t < NPB) sg[t] = batch[blockIdx.x * NPB + t];
        __syncthreads();
        if (t < H_DIM) {                   // segmented reduce over 16 sorted nodes
            int j = t;
            int g = sg[0];
            float mx = agg[0][j], sm = mx;
            int run = 1;
            for (int nn = 1; nn < NPB; ++nn) {
                float v = agg[nn][j];
                if (sg[nn] != g) {
                    atomicMax(&gmaxk[g * H_DIM + j], fenc(mx));
                    atomicAdd(&gsum[g * H_DIM + j], sm);
                    if (j == 0) atomicAdd(&gcnt[g], run);
                    g = sg[nn]; mx = v; sm = v; run = 1;
                } else {
                    mx = fmaxf(mx, v); sm += v; ++run;
                }
            }
            atomicMax(&gmaxk[g * H_DIM + j], fenc(mx));
            atomicAdd(&gsum[g * H_DIM + j], sm);
            if (j == 0) atomicAdd(&gcnt[g], run);
        }
    }
}

// ---------------------------------------------------------------------------
// Head: decode per-graph accumulators -> pooled[96] + linear head.
__global__ __launch_bounds__(256) void head_kernel(const unsigned* __restrict__ gmaxk,
                                                   const float* __restrict__ gsum,
                                                   const int* __restrict__ gcnt,
                                                   const float* __restrict__ Wout,
                                                   const float* __restrict__ bout,
                                                   float* __restrict__ out) {
    __shared__ float sWo[3 * H_DIM];
    int b = threadIdx.x;                   // one thread per graph, 256 threads
    if (b < 3 * H_DIM) sWo[b] = Wout[b];
    __syncthreads();
    float cnt = fmaxf((float)gcnt[b], 1.0f);
    float acc = 0.f;
    float* po = out + B_GRAPHS + (size_t)b * 96;
#pragma unroll
    for (int j = 0; j < H_DIM; ++j) {
        float mx = fdec(gmaxk[b * H_DIM + j]);
        float sm = gsum[b * H_DIM + j];
        float mean = sm / cnt;
        po[j]      = mx;
        po[32 + j] = mean;
        po[64 + j] = sm;
        acc += mx * sWo[j] + mean * sWo[32 + j] + sm * sWo[64 + j];
    }
    out[b] = acc + bout[0];
}

// ---------------------------------------------------------------------------
extern "C" void kernel_launch(void* const* d_in, const int* in_sizes, int n_in,
                              void* d_out, int out_size, void* d_ws, size_t ws_size,
                              hipStream_t stream) {
    const float* x     = (const float*)d_in[0];
    const int*   ei    = (const int*)  d_in[1];   // src = ei[0:E], dst = ei[E:2E]
    const int*   batch = (const int*)  d_in[2];
    const float* W0    = (const float*)d_in[3];
    const float* b0    = (const float*)d_in[4];
    const float* W1    = (const float*)d_in[5];
    const float* b1    = (const float*)d_in[6];
    const float* W2    = (const float*)d_in[7];
    const float* b2    = (const float*)d_in[8];
    const float* W3    = (const float*)d_in[9];
    const float* b3    = (const float*)d_in[10];
    const float* Wout  = (const float*)d_in[11];
    const float* bout  = (const float*)d_in[12];
    float* out = (float*)d_out;

    char* p = (char*)d_ws;
    float*    dinv       = (float*)p;    p += (size_t)N_NODES * 4;            // 16B-mult
    unsigned* hA         = (unsigned*)p; p += (size_t)N_NODES * 16 * 4;
    unsigned* rec        = (unsigned*)p; p += (size_t)NBUCKET * CAPB * 4;     // 8 MB, reused as hB
    int2*     csr        = (int2*)p;     p += (size_t)TPAD * 8;               // 18.4 MB
    int2*     row_meta   = (int2*)p;     p += (size_t)N_NODES * 8;
    int*      bucket_cur = (int*)p;      p += (size_t)NBUCKET * CURSTR * 4;
    unsigned* gmaxk      = (unsigned*)p; p += (size_t)B_GRAPHS * H_DIM * 4;
    float*    gsumA      = (float*)p;    p += (size_t)B_GRAPHS * H_DIM * 4;
    int*      gcnt       = (int*)p;      p += (size_t)B_GRAPHS * 4;
    unsigned* hB = rec;   // alias: rec dead once passC completes

    // ---- edge build: fixed-stride buckets -> per-bucket node sort -> CSR ----
    init_kernel<<<(N_NODES + 255) / 256, 256, 0, stream>>>(bucket_cur, gmaxk, gsumA, gcnt);
    passB_kernel<<<NCHUNK, 1024, 0, stream>>>(ei, bucket_cur, rec);
    dinv_kernel<<<NBUCKET, 256, 0, stream>>>(rec, bucket_cur, dinv);
    passC_kernel<<<NBUCKET, 256, 0, stream>>>(rec, bucket_cur, dinv, row_meta, csr);

    // ---- 4 GCN layers (gather, no atomics, int4 csr, plain loads) ----
    layer_kernel<F_IN, false, false><<<LAYER_BLOCKS, 256, 0, stream>>>(
        x,  row_meta, (const int4*)csr, dinv, W0, b0, hA, nullptr, nullptr, nullptr, nullptr);
    layer_kernel<H_DIM, true, false><<<LAYER_BLOCKS, 256, 0, stream>>>(
        hA, row_meta, (const int4*)csr, dinv, W1, b1, hB, nullptr, nullptr, nullptr, nullptr);
    layer_kernel<H_DIM, true, false><<<LAYER_BLOCKS, 256, 0, stream>>>(
        hB, row_meta, (const int4*)csr, dinv, W2, b2, hA, nullptr, nullptr, nullptr, nullptr);
    // layer 4: fused pooling (no h store, no pool kernel re-read)
    layer_kernel<H_DIM, true, true><<<LAYER_BLOCKS, 256, 0, stream>>>(
        hA, row_meta, (const int4*)csr, dinv, W3, b3, hB, batch, gmaxk, gsumA, gcnt);

    head_kernel<<<1, 256, 0, stream>>>(gmaxk, gsumA, gcnt, Wout, bout, out);
}